// Round 1
// baseline (3116.006 us; speedup 1.0000x reference)
//
#include <hip/hip_runtime.h>

#define MAXD 10
#define TSTEPS 4
#define KD 80      // IN + EC
#define IN 64
#define ECH 16
#define TILE_E 128

// ---------------- preprocessing ----------------

__global__ __launch_bounds__(256) void deg_init_kernel(int* deg, int N) {
    int i = blockIdx.x * 256 + threadIdx.x;
    if (i < N) deg[i] = 1;  // self loop
}

__global__ __launch_bounds__(256) void deg_add_kernel(const int* __restrict__ ei, int* deg, int E) {
    int e = blockIdx.x * 256 + threadIdx.x;
    if (e < E) atomicAdd(&deg[ei[e]], 1);
}

__global__ __launch_bounds__(256) void count_kernel(const int* __restrict__ ei, const int* __restrict__ deg,
                                                    int* cnt, int E, int Etot) {
    int e = blockIdx.x * 256 + threadIdx.x;
    if (e >= Etot) return;
    int s = (e < E) ? ei[e] : (e - E);
    int dg = deg[s];
    int b = (dg < MAXD ? dg : MAXD) - 1;
    atomicAdd(&cnt[b], 1);
}

__global__ void scan_kernel(const int* __restrict__ cnt, int* cursor) {
    if (threadIdx.x == 0) {
        int acc = 0;
        for (int b = 0; b < MAXD; ++b) { cursor[b] = acc; acc += cnt[b]; }
    }
}

__global__ __launch_bounds__(256) void scatter_kernel(
    const int* __restrict__ ei, const float* __restrict__ ea, const int* __restrict__ deg,
    int* cursor, int* s_sorted, int* d_sorted, int* b_sorted, float* ea_sorted,
    int E, int Etot)
{
    int e = blockIdx.x * 256 + threadIdx.x;
    if (e >= Etot) return;
    int s, d;
    if (e < E) { s = ei[e]; d = ei[E + e]; } else { s = e - E; d = s; }
    int dg = deg[s];
    int b = (dg < MAXD ? dg : MAXD) - 1;
    int pos = atomicAdd(&cursor[b], 1);
    s_sorted[pos] = s;
    d_sorted[pos] = d;
    b_sorted[pos] = b;
    float4* o = (float4*)(ea_sorted + (size_t)pos * ECH);
    if (e < E) {
        const float4* p = (const float4*)(ea + (size_t)e * ECH);
        o[0] = p[0]; o[1] = p[1]; o[2] = p[2]; o[3] = p[3];
    } else {
        float4 z = make_float4(0.f, 0.f, 0.f, 0.f);
        o[0] = z; o[1] = z; o[2] = z; o[3] = z;
    }
}

// ---------------- message passing GEMM ----------------
// Block: 256 threads, 128 edges. W[bucket] (80x64) in LDS, mi^T (80x132 padded) in LDS.
// Thread (eg,cg) accumulates 8 edges x 4 cols in registers.

__global__ __launch_bounds__(256) void msg_kernel(
    const float* __restrict__ xin, float* __restrict__ xout,
    const int* __restrict__ s_sorted, const int* __restrict__ d_sorted,
    const int* __restrict__ b_sorted, const float* __restrict__ ea_sorted,
    const float* __restrict__ Wt, int Etot)
{
    __shared__ float Ws[KD][IN];           // 20 KB
    __shared__ float Ms[KD][TILE_E + 4];   // 42.2 KB, pad -> conflict-free transpose write
    __shared__ int dst_s[TILE_E];
    __shared__ int bkt_s[TILE_E];

    const int t = threadIdx.x;
    const int i0 = blockIdx.x * TILE_E;
    const int ntile = min(TILE_E, Etot - i0);

    // stage mi^T: rows 0..63 = x[src], rows 64..79 = edge_attr
    {
        const int e = t >> 1;
        const bool valid = e < ntile;
        const int c0 = (t & 1) * 32;
        const float4 z4 = make_float4(0.f, 0.f, 0.f, 0.f);
        int s = valid ? s_sorted[i0 + e] : 0;
        const float* xp = xin + (size_t)s * IN + c0;
        #pragma unroll
        for (int i = 0; i < 32; i += 4) {
            float4 v = valid ? *(const float4*)(xp + i) : z4;
            Ms[c0 + i + 0][e] = v.x; Ms[c0 + i + 1][e] = v.y;
            Ms[c0 + i + 2][e] = v.z; Ms[c0 + i + 3][e] = v.w;
        }
        const int j0 = (t & 1) * 8;
        const float* ep = ea_sorted + (size_t)(i0 + e) * ECH + j0;
        #pragma unroll
        for (int i = 0; i < 8; i += 4) {
            float4 v = valid ? *(const float4*)(ep + i) : z4;
            Ms[IN + j0 + i + 0][e] = v.x; Ms[IN + j0 + i + 1][e] = v.y;
            Ms[IN + j0 + i + 2][e] = v.z; Ms[IN + j0 + i + 3][e] = v.w;
        }
        if (t < TILE_E) {
            dst_s[t] = (t < ntile) ? d_sorted[i0 + t] : 0;
            bkt_s[t] = (t < ntile) ? b_sorted[i0 + t] : -1;
        }
    }
    __syncthreads();

    const int b_first = bkt_s[0];
    const int b_last = bkt_s[ntile - 1];
    const int eg8 = (t >> 4) * 8;
    const int cg4 = (t & 15) * 4;

    for (int b = b_first; b <= b_last; ++b) {
        if (b != b_first) __syncthreads();
        {
            const float4* Wb = (const float4*)(Wt + (size_t)b * KD * IN);
            float4* Wsp = (float4*)Ws;
            for (int q = t; q < KD * IN / 4; q += 256) Wsp[q] = Wb[q];
        }
        __syncthreads();

        float acc[8][4];
        #pragma unroll
        for (int e2 = 0; e2 < 8; ++e2)
            #pragma unroll
            for (int c = 0; c < 4; ++c) acc[e2][c] = 0.f;

        #pragma unroll 8
        for (int k = 0; k < KD; ++k) {
            const float4 w  = *(const float4*)&Ws[k][cg4];
            const float4 m0 = *(const float4*)&Ms[k][eg8];
            const float4 m1 = *(const float4*)&Ms[k][eg8 + 4];
            const float me[8] = {m0.x, m0.y, m0.z, m0.w, m1.x, m1.y, m1.z, m1.w};
            #pragma unroll
            for (int e2 = 0; e2 < 8; ++e2) {
                acc[e2][0] += me[e2] * w.x;
                acc[e2][1] += me[e2] * w.y;
                acc[e2][2] += me[e2] * w.z;
                acc[e2][3] += me[e2] * w.w;
            }
        }

        #pragma unroll
        for (int e2 = 0; e2 < 8; ++e2) {
            const int el = eg8 + e2;
            if (el < ntile && bkt_s[el] == b) {
                float* op = xout + (size_t)dst_s[el] * IN + cg4;
                #pragma unroll
                for (int c = 0; c < 4; ++c) {
                    float v = 1.0f / (1.0f + __expf(-acc[e2][c]));
                    atomicAdd(op + c, v);
                }
            }
        }
    }
}

// ---------------- readout + pooling ----------------

__global__ __launch_bounds__(256) void readout_kernel(
    const float* __restrict__ x, const float* __restrict__ Wr,
    const int* __restrict__ batch, float* __restrict__ pooled, int N)
{
    __shared__ float Wr_s[TSTEPS][10][IN];  // transposed [t][j][k]
    __shared__ float pool_s[64 * 10];
    const int t = threadIdx.x;
    for (int idx = t; idx < TSTEPS * IN * 10; idx += 256) {
        int tt = idx / (IN * 10);
        int r = idx % (IN * 10);
        int k = r / 10;
        int j = r % 10;
        Wr_s[tt][j][k] = Wr[idx];
    }
    for (int idx = t; idx < 64 * 10; idx += 256) pool_s[idx] = 0.f;
    __syncthreads();

    const int n = blockIdx.x * 256 + t;
    if (n < N) {
        float xr[IN];
        const float4* xp = (const float4*)(x + (size_t)n * IN);
        #pragma unroll
        for (int i = 0; i < IN / 4; ++i) ((float4*)xr)[i] = xp[i];
        float out10[10];
        #pragma unroll
        for (int j = 0; j < 10; ++j) out10[j] = 0.f;
        for (int tt = 0; tt < TSTEPS; ++tt) {
            float lg[10];
            #pragma unroll
            for (int j = 0; j < 10; ++j) {
                const float4* wp = (const float4*)Wr_s[tt][j];
                float s = 0.f;
                #pragma unroll
                for (int i = 0; i < IN / 4; ++i) {
                    float4 w = wp[i];
                    float4 xv = ((const float4*)xr)[i];
                    s += w.x * xv.x + w.y * xv.y + w.z * xv.z + w.w * xv.w;
                }
                lg[j] = s;
            }
            float mx = lg[0];
            #pragma unroll
            for (int j = 1; j < 10; ++j) mx = fmaxf(mx, lg[j]);
            float sum = 0.f;
            #pragma unroll
            for (int j = 0; j < 10; ++j) { lg[j] = __expf(lg[j] - mx); sum += lg[j]; }
            float inv = 1.f / sum;
            #pragma unroll
            for (int j = 0; j < 10; ++j) out10[j] += lg[j] * inv;
        }
        const int g = batch[n];
        #pragma unroll
        for (int j = 0; j < 10; ++j) atomicAdd(&pool_s[g * 10 + j], out10[j]);
    }
    __syncthreads();
    for (int idx = t; idx < 64 * 10; idx += 256) {
        float v = pool_s[idx];
        if (v != 0.f) atomicAdd(&pooled[idx], v);
    }
}

// ---------------- final MLP ----------------

__global__ __launch_bounds__(256) void mlp_kernel(
    const float* __restrict__ pooled,
    const float* __restrict__ fc1w, const float* __restrict__ fc1b,
    const float* __restrict__ fc2w, const float* __restrict__ fc2b,
    const float* __restrict__ fc3w, const float* __restrict__ fc3b,
    float* __restrict__ out, int G)
{
    __shared__ float p_s[64 * 10];
    __shared__ float h1[64 * 128];
    __shared__ float h2[64 * 64];
    const int t = threadIdx.x;
    for (int idx = t; idx < G * 10; idx += 256) p_s[idx] = pooled[idx];
    __syncthreads();
    for (int idx = t; idx < G * 128; idx += 256) {
        int g = idx >> 7, j = idx & 127;
        float s = fc1b[j];
        #pragma unroll
        for (int k = 0; k < 10; ++k) s += p_s[g * 10 + k] * fc1w[k * 128 + j];
        h1[idx] = (s > 0.f) ? s : 0.01f * s;
    }
    __syncthreads();
    for (int idx = t; idx < G * 64; idx += 256) {
        int g = idx >> 6, j = idx & 63;
        float s = fc2b[j];
        for (int k = 0; k < 128; ++k) s += h1[(g << 7) + k] * fc2w[(k << 6) + j];
        h2[idx] = (s > 0.f) ? s : 0.01f * s;
    }
    __syncthreads();
    if (t < G) {
        float s = fc3b[0];
        for (int k = 0; k < 64; ++k) s += h2[(t << 6) + k] * fc3w[k];
        out[t] = (s > 0.f) ? s : 0.01f * s;
    }
}

// ---------------- launch ----------------

extern "C" void kernel_launch(void* const* d_in, const int* in_sizes, int n_in,
                              void* d_out, int out_size, void* d_ws, size_t ws_size,
                              hipStream_t stream)
{
    const float* x     = (const float*)d_in[0];
    const float* ea    = (const float*)d_in[1];
    const float* Wmsg  = (const float*)d_in[2];
    const float* Wread = (const float*)d_in[3];
    const float* fc1w  = (const float*)d_in[4];
    const float* fc1b  = (const float*)d_in[5];
    const float* fc2w  = (const float*)d_in[6];
    const float* fc2b  = (const float*)d_in[7];
    const float* fc3w  = (const float*)d_in[8];
    const float* fc3b  = (const float*)d_in[9];
    const int* ei      = (const int*)d_in[10];
    const int* batch   = (const int*)d_in[11];

    const int N = in_sizes[0] / IN;
    const int E = in_sizes[10] / 2;
    const int Etot = E + N;

    char* ws = (char*)d_ws;
    size_t off = 0;
    auto take = [&](size_t bytes) {
        char* p = ws + off;
        off = (off + bytes + 255) & ~(size_t)255;
        return p;
    };
    int* deg         = (int*)take((size_t)N * 4);
    int* meta        = (int*)take(128);   // [0..9]=cnt, [16..25]=cursor
    int* s_sorted    = (int*)take((size_t)Etot * 4);
    int* d_sorted    = (int*)take((size_t)Etot * 4);
    int* b_sorted    = (int*)take((size_t)Etot * 4);
    float* ea_sorted = (float*)take((size_t)Etot * ECH * 4);
    float* xbA       = (float*)take((size_t)N * IN * 4);
    float* xbB       = (float*)take((size_t)N * IN * 4);
    float* pooled    = (float*)take(64 * 10 * 4);

    int* cnt = meta;
    int* cursor = meta + 16;

    hipMemsetAsync(meta, 0, 128, stream);
    deg_init_kernel<<<(N + 255) / 256, 256, 0, stream>>>(deg, N);
    deg_add_kernel<<<(E + 255) / 256, 256, 0, stream>>>(ei, deg, E);
    count_kernel<<<(Etot + 255) / 256, 256, 0, stream>>>(ei, deg, cnt, E, Etot);
    scan_kernel<<<1, 64, 0, stream>>>(cnt, cursor);
    scatter_kernel<<<(Etot + 255) / 256, 256, 0, stream>>>(
        ei, ea, deg, cursor, s_sorted, d_sorted, b_sorted, ea_sorted, E, Etot);

    const int nblk = (Etot + TILE_E - 1) / TILE_E;
    const float* xi = x;
    float* bufs[2] = {xbA, xbB};
    for (int tt = 0; tt < TSTEPS; ++tt) {
        float* xo = bufs[tt & 1];
        hipMemsetAsync(xo, 0, (size_t)N * IN * 4, stream);
        msg_kernel<<<nblk, 256, 0, stream>>>(xi, xo, s_sorted, d_sorted, b_sorted,
                                             ea_sorted, Wmsg + (size_t)tt * MAXD * KD * IN, Etot);
        xi = xo;
    }

    hipMemsetAsync(pooled, 0, 64 * 10 * 4, stream);
    readout_kernel<<<(N + 255) / 256, 256, 0, stream>>>(xi, Wread, batch, pooled, N);
    mlp_kernel<<<1, 256, 0, stream>>>(pooled, fc1w, fc1b, fc2w, fc2b, fc3w, fc3b,
                                      (float*)d_out, out_size);
}

// Round 2
// 824.094 us; speedup vs baseline: 3.7811x; 3.7811x over previous
//
#include <hip/hip_runtime.h>

#define MAXD 10
#define TSTEPS 4
#define KD 80      // IN + EC
#define IN 64
#define ECH 16
#define TILE_E 128

// ---------------- preprocessing ----------------

__global__ __launch_bounds__(256) void deg_init_kernel(int* deg, int N) {
    int i = blockIdx.x * 256 + threadIdx.x;
    if (i < N) deg[i] = 1;  // self loop
}

__global__ __launch_bounds__(256) void deg_add_kernel(const int* __restrict__ ei, int* deg, int E) {
    int e = blockIdx.x * 256 + threadIdx.x;
    if (e < E) atomicAdd(&deg[ei[e]], 1);
}

// LDS-aggregated histogram: 10 global atomics per block instead of 256
__global__ __launch_bounds__(256) void count_kernel(const int* __restrict__ ei, const int* __restrict__ deg,
                                                    int* cnt, int E, int Etot) {
    __shared__ int h[MAXD];
    const int t = threadIdx.x;
    if (t < MAXD) h[t] = 0;
    __syncthreads();
    int e = blockIdx.x * 256 + t;
    if (e < Etot) {
        int s = (e < E) ? ei[e] : (e - E);
        int dg = deg[s];
        int b = (dg < MAXD ? dg : MAXD) - 1;
        atomicAdd(&h[b], 1);
    }
    __syncthreads();
    if (t < MAXD && h[t] > 0) atomicAdd(&cnt[t], h[t]);
}

__global__ void scan_kernel(const int* __restrict__ cnt, int* cursor) {
    if (threadIdx.x == 0) {
        int acc = 0;
        for (int b = 0; b < MAXD; ++b) { cursor[b] = acc; acc += cnt[b]; }
    }
}

// LDS-aggregated scatter: per-block LDS histogram -> one global atomicAdd per
// bucket per block to reserve a contiguous range, then LDS-local offsets.
__global__ __launch_bounds__(256) void scatter_kernel(
    const int* __restrict__ ei, const float* __restrict__ ea, const int* __restrict__ deg,
    int* cursor, int* s_sorted, int* d_sorted, int* b_sorted, float* ea_sorted,
    int E, int Etot)
{
    __shared__ int h[MAXD];
    __shared__ int base[MAXD];
    const int t = threadIdx.x;
    if (t < MAXD) h[t] = 0;
    __syncthreads();

    const int e = blockIdx.x * 256 + t;
    int s = 0, d = 0, b = 0, loc = 0;
    const bool valid = e < Etot;
    if (valid) {
        if (e < E) { s = ei[e]; d = ei[E + e]; } else { s = e - E; d = s; }
        int dg = deg[s];
        b = (dg < MAXD ? dg : MAXD) - 1;
        loc = atomicAdd(&h[b], 1);
    }
    __syncthreads();
    if (t < MAXD) base[t] = (h[t] > 0) ? atomicAdd(&cursor[t], h[t]) : 0;
    __syncthreads();

    if (valid) {
        int pos = base[b] + loc;
        s_sorted[pos] = s;
        d_sorted[pos] = d;
        b_sorted[pos] = b;
        float4* o = (float4*)(ea_sorted + (size_t)pos * ECH);
        if (e < E) {
            const float4* p = (const float4*)(ea + (size_t)e * ECH);
            o[0] = p[0]; o[1] = p[1]; o[2] = p[2]; o[3] = p[3];
        } else {
            float4 z = make_float4(0.f, 0.f, 0.f, 0.f);
            o[0] = z; o[1] = z; o[2] = z; o[3] = z;
        }
    }
}

// ---------------- message passing GEMM ----------------
// Block: 256 threads, 128 edges. W[bucket] (80x64) in LDS, mi^T (80x132 padded) in LDS.
// Thread (eg,cg) accumulates 8 edges x 4 cols in registers.

__global__ __launch_bounds__(256) void msg_kernel(
    const float* __restrict__ xin, float* __restrict__ xout,
    const int* __restrict__ s_sorted, const int* __restrict__ d_sorted,
    const int* __restrict__ b_sorted, const float* __restrict__ ea_sorted,
    const float* __restrict__ Wt, int Etot)
{
    __shared__ float Ws[KD][IN];           // 20 KB
    __shared__ float Ms[KD][TILE_E + 4];   // 42.2 KB, pad -> conflict-free transpose write
    __shared__ int dst_s[TILE_E];
    __shared__ int bkt_s[TILE_E];

    const int t = threadIdx.x;
    const int i0 = blockIdx.x * TILE_E;
    const int ntile = min(TILE_E, Etot - i0);

    // stage mi^T: rows 0..63 = x[src], rows 64..79 = edge_attr
    {
        const int e = t >> 1;
        const bool valid = e < ntile;
        const int c0 = (t & 1) * 32;
        const float4 z4 = make_float4(0.f, 0.f, 0.f, 0.f);
        int s = valid ? s_sorted[i0 + e] : 0;
        const float* xp = xin + (size_t)s * IN + c0;
        #pragma unroll
        for (int i = 0; i < 32; i += 4) {
            float4 v = valid ? *(const float4*)(xp + i) : z4;
            Ms[c0 + i + 0][e] = v.x; Ms[c0 + i + 1][e] = v.y;
            Ms[c0 + i + 2][e] = v.z; Ms[c0 + i + 3][e] = v.w;
        }
        const int j0 = (t & 1) * 8;
        const float* ep = ea_sorted + (size_t)(i0 + e) * ECH + j0;
        #pragma unroll
        for (int i = 0; i < 8; i += 4) {
            float4 v = valid ? *(const float4*)(ep + i) : z4;
            Ms[IN + j0 + i + 0][e] = v.x; Ms[IN + j0 + i + 1][e] = v.y;
            Ms[IN + j0 + i + 2][e] = v.z; Ms[IN + j0 + i + 3][e] = v.w;
        }
        if (t < TILE_E) {
            dst_s[t] = (t < ntile) ? d_sorted[i0 + t] : 0;
            bkt_s[t] = (t < ntile) ? b_sorted[i0 + t] : -1;
        }
    }
    __syncthreads();

    const int b_first = bkt_s[0];
    const int b_last = bkt_s[ntile - 1];
    const int eg8 = (t >> 4) * 8;
    const int cg4 = (t & 15) * 4;

    for (int b = b_first; b <= b_last; ++b) {
        if (b != b_first) __syncthreads();
        {
            const float4* Wb = (const float4*)(Wt + (size_t)b * KD * IN);
            float4* Wsp = (float4*)Ws;
            for (int q = t; q < KD * IN / 4; q += 256) Wsp[q] = Wb[q];
        }
        __syncthreads();

        float acc[8][4];
        #pragma unroll
        for (int e2 = 0; e2 < 8; ++e2)
            #pragma unroll
            for (int c = 0; c < 4; ++c) acc[e2][c] = 0.f;

        #pragma unroll 8
        for (int k = 0; k < KD; ++k) {
            const float4 w  = *(const float4*)&Ws[k][cg4];
            const float4 m0 = *(const float4*)&Ms[k][eg8];
            const float4 m1 = *(const float4*)&Ms[k][eg8 + 4];
            const float me[8] = {m0.x, m0.y, m0.z, m0.w, m1.x, m1.y, m1.z, m1.w};
            #pragma unroll
            for (int e2 = 0; e2 < 8; ++e2) {
                acc[e2][0] += me[e2] * w.x;
                acc[e2][1] += me[e2] * w.y;
                acc[e2][2] += me[e2] * w.z;
                acc[e2][3] += me[e2] * w.w;
            }
        }

        #pragma unroll
        for (int e2 = 0; e2 < 8; ++e2) {
            const int el = eg8 + e2;
            if (el < ntile && bkt_s[el] == b) {
                float* op = xout + (size_t)dst_s[el] * IN + cg4;
                #pragma unroll
                for (int c = 0; c < 4; ++c) {
                    float v = 1.0f / (1.0f + __expf(-acc[e2][c]));
                    atomicAdd(op + c, v);
                }
            }
        }
    }
}

// ---------------- readout + pooling ----------------

__global__ __launch_bounds__(256) void readout_kernel(
    const float* __restrict__ x, const float* __restrict__ Wr,
    const int* __restrict__ batch, float* __restrict__ pooled, int N)
{
    __shared__ float Wr_s[TSTEPS][10][IN];  // transposed [t][j][k]
    __shared__ float pool_s[64 * 10];
    const int t = threadIdx.x;
    for (int idx = t; idx < TSTEPS * IN * 10; idx += 256) {
        int tt = idx / (IN * 10);
        int r = idx % (IN * 10);
        int k = r / 10;
        int j = r % 10;
        Wr_s[tt][j][k] = Wr[idx];
    }
    for (int idx = t; idx < 64 * 10; idx += 256) pool_s[idx] = 0.f;
    __syncthreads();

    const int n = blockIdx.x * 256 + t;
    if (n < N) {
        float xr[IN];
        const float4* xp = (const float4*)(x + (size_t)n * IN);
        #pragma unroll
        for (int i = 0; i < IN / 4; ++i) ((float4*)xr)[i] = xp[i];
        float out10[10];
        #pragma unroll
        for (int j = 0; j < 10; ++j) out10[j] = 0.f;
        for (int tt = 0; tt < TSTEPS; ++tt) {
            float lg[10];
            #pragma unroll
            for (int j = 0; j < 10; ++j) {
                const float4* wp = (const float4*)Wr_s[tt][j];
                float s = 0.f;
                #pragma unroll
                for (int i = 0; i < IN / 4; ++i) {
                    float4 w = wp[i];
                    float4 xv = ((const float4*)xr)[i];
                    s += w.x * xv.x + w.y * xv.y + w.z * xv.z + w.w * xv.w;
                }
                lg[j] = s;
            }
            float mx = lg[0];
            #pragma unroll
            for (int j = 1; j < 10; ++j) mx = fmaxf(mx, lg[j]);
            float sum = 0.f;
            #pragma unroll
            for (int j = 0; j < 10; ++j) { lg[j] = __expf(lg[j] - mx); sum += lg[j]; }
            float inv = 1.f / sum;
            #pragma unroll
            for (int j = 0; j < 10; ++j) out10[j] += lg[j] * inv;
        }
        const int g = batch[n];
        #pragma unroll
        for (int j = 0; j < 10; ++j) atomicAdd(&pool_s[g * 10 + j], out10[j]);
    }
    __syncthreads();
    for (int idx = t; idx < 64 * 10; idx += 256) {
        float v = pool_s[idx];
        if (v != 0.f) atomicAdd(&pooled[idx], v);
    }
}

// ---------------- final MLP ----------------

__global__ __launch_bounds__(256) void mlp_kernel(
    const float* __restrict__ pooled,
    const float* __restrict__ fc1w, const float* __restrict__ fc1b,
    const float* __restrict__ fc2w, const float* __restrict__ fc2b,
    const float* __restrict__ fc3w, const float* __restrict__ fc3b,
    float* __restrict__ out, int G)
{
    __shared__ float p_s[64 * 10];
    __shared__ float h1[64 * 128];
    __shared__ float h2[64 * 64];
    const int t = threadIdx.x;
    for (int idx = t; idx < G * 10; idx += 256) p_s[idx] = pooled[idx];
    __syncthreads();
    for (int idx = t; idx < G * 128; idx += 256) {
        int g = idx >> 7, j = idx & 127;
        float s = fc1b[j];
        #pragma unroll
        for (int k = 0; k < 10; ++k) s += p_s[g * 10 + k] * fc1w[k * 128 + j];
        h1[idx] = (s > 0.f) ? s : 0.01f * s;
    }
    __syncthreads();
    for (int idx = t; idx < G * 64; idx += 256) {
        int g = idx >> 6, j = idx & 63;
        float s = fc2b[j];
        for (int k = 0; k < 128; ++k) s += h1[(g << 7) + k] * fc2w[(k << 6) + j];
        h2[idx] = (s > 0.f) ? s : 0.01f * s;
    }
    __syncthreads();
    if (t < G) {
        float s = fc3b[0];
        for (int k = 0; k < 64; ++k) s += h2[(t << 6) + k] * fc3w[k];
        out[t] = (s > 0.f) ? s : 0.01f * s;
    }
}

// ---------------- launch ----------------

extern "C" void kernel_launch(void* const* d_in, const int* in_sizes, int n_in,
                              void* d_out, int out_size, void* d_ws, size_t ws_size,
                              hipStream_t stream)
{
    const float* x     = (const float*)d_in[0];
    const float* ea    = (const float*)d_in[1];
    const float* Wmsg  = (const float*)d_in[2];
    const float* Wread = (const float*)d_in[3];
    const float* fc1w  = (const float*)d_in[4];
    const float* fc1b  = (const float*)d_in[5];
    const float* fc2w  = (const float*)d_in[6];
    const float* fc2b  = (const float*)d_in[7];
    const float* fc3w  = (const float*)d_in[8];
    const float* fc3b  = (const float*)d_in[9];
    const int* ei      = (const int*)d_in[10];
    const int* batch   = (const int*)d_in[11];

    const int N = in_sizes[0] / IN;
    const int E = in_sizes[10] / 2;
    const int Etot = E + N;

    char* ws = (char*)d_ws;
    size_t off = 0;
    auto take = [&](size_t bytes) {
        char* p = ws + off;
        off = (off + bytes + 255) & ~(size_t)255;
        return p;
    };
    int* deg         = (int*)take((size_t)N * 4);
    int* meta        = (int*)take(128);   // [0..9]=cnt, [16..25]=cursor
    int* s_sorted    = (int*)take((size_t)Etot * 4);
    int* d_sorted    = (int*)take((size_t)Etot * 4);
    int* b_sorted    = (int*)take((size_t)Etot * 4);
    float* ea_sorted = (float*)take((size_t)Etot * ECH * 4);
    float* xbA       = (float*)take((size_t)N * IN * 4);
    float* xbB       = (float*)take((size_t)N * IN * 4);
    float* pooled    = (float*)take(64 * 10 * 4);

    int* cnt = meta;
    int* cursor = meta + 16;

    hipMemsetAsync(meta, 0, 128, stream);
    deg_init_kernel<<<(N + 255) / 256, 256, 0, stream>>>(deg, N);
    deg_add_kernel<<<(E + 255) / 256, 256, 0, stream>>>(ei, deg, E);
    count_kernel<<<(Etot + 255) / 256, 256, 0, stream>>>(ei, deg, cnt, E, Etot);
    scan_kernel<<<1, 64, 0, stream>>>(cnt, cursor);
    scatter_kernel<<<(Etot + 255) / 256, 256, 0, stream>>>(
        ei, ea, deg, cursor, s_sorted, d_sorted, b_sorted, ea_sorted, E, Etot);

    const int nblk = (Etot + TILE_E - 1) / TILE_E;
    const float* xi = x;
    float* bufs[2] = {xbA, xbB};
    for (int tt = 0; tt < TSTEPS; ++tt) {
        float* xo = bufs[tt & 1];
        hipMemsetAsync(xo, 0, (size_t)N * IN * 4, stream);
        msg_kernel<<<nblk, 256, 0, stream>>>(xi, xo, s_sorted, d_sorted, b_sorted,
                                             ea_sorted, Wmsg + (size_t)tt * MAXD * KD * IN, Etot);
        xi = xo;
    }

    hipMemsetAsync(pooled, 0, 64 * 10 * 4, stream);
    readout_kernel<<<(N + 255) / 256, 256, 0, stream>>>(xi, Wread, batch, pooled, N);
    mlp_kernel<<<1, 256, 0, stream>>>(pooled, fc1w, fc1b, fc2w, fc2b, fc3w, fc3b,
                                      (float*)d_out, out_size);
}

// Round 3
// 439.950 us; speedup vs baseline: 7.0826x; 1.8732x over previous
//
#include <hip/hip_runtime.h>

#define MAXD 10
#define TSTEPS 4
#define KD 80      // IN + EC
#define IN 64
#define ECH 16
#define TILE_N 64  // nodes per block in y_kernel
#define DPB 16     // dsts per block in agg_kernel (4 per wave)

__device__ __forceinline__ float sigmoidf(float v) {
    return 1.0f / (1.0f + __expf(-v));
}

// ---------------- preprocessing ----------------

__global__ __launch_bounds__(256) void deg_init_kernel(int* deg, int N) {
    int i = blockIdx.x * 256 + threadIdx.x;
    if (i < N) deg[i] = 1;  // self loop
}

__global__ __launch_bounds__(256) void deg_add_kernel(const int* __restrict__ ei, int* deg, int E) {
    int e = blockIdx.x * 256 + threadIdx.x;
    if (e < E) atomicAdd(&deg[ei[e]], 1);
}

// node bucket histogram (LDS-aggregated)
__global__ __launch_bounds__(256) void nb_count_kernel(const int* __restrict__ deg, int* cnt, int N) {
    __shared__ int h[MAXD];
    const int t = threadIdx.x;
    if (t < MAXD) h[t] = 0;
    __syncthreads();
    int n = blockIdx.x * 256 + t;
    if (n < N) {
        int dg = deg[n];
        int b = (dg < MAXD ? dg : MAXD) - 1;
        atomicAdd(&h[b], 1);
    }
    __syncthreads();
    if (t < MAXD && h[t] > 0) atomicAdd(&cnt[t], h[t]);
}

__global__ void nb_scan_kernel(const int* __restrict__ cnt, int* cursor) {
    if (threadIdx.x == 0) {
        int acc = 0;
        for (int b = 0; b < MAXD; ++b) { cursor[b] = acc; acc += cnt[b]; }
    }
}

// scatter nodes into bucket-sorted list (LDS-aggregated cursor)
__global__ __launch_bounds__(256) void nb_scatter_kernel(const int* __restrict__ deg,
                                                         int* cursor, int* node_list, int N) {
    __shared__ int h[MAXD];
    __shared__ int base[MAXD];
    const int t = threadIdx.x;
    if (t < MAXD) h[t] = 0;
    __syncthreads();
    const int n = blockIdx.x * 256 + t;
    int b = 0, loc = 0;
    const bool valid = n < N;
    if (valid) {
        int dg = deg[n];
        b = (dg < MAXD ? dg : MAXD) - 1;
        loc = atomicAdd(&h[b], 1);
    }
    __syncthreads();
    if (t < MAXD) base[t] = (h[t] > 0) ? atomicAdd(&cursor[t], h[t]) : 0;
    __syncthreads();
    if (valid) node_list[base[b] + loc] = n;
}

// in-degree histogram over dst
__global__ __launch_bounds__(256) void in_hist_kernel(const int* __restrict__ ei, int* in_cnt, int E) {
    int e = blockIdx.x * 256 + threadIdx.x;
    if (e < E) atomicAdd(&in_cnt[ei[E + e]], 1);
}

// single-block exclusive scan of in_cnt[0..N) -> row_ptr[0..N], copy to cursor
__global__ __launch_bounds__(256) void rp_scan_kernel(const int* __restrict__ in_cnt,
                                                      int* row_ptr, int* cursor, int N) {
    __shared__ int part[256];
    const int t = threadIdx.x;
    const int chunk = (N + 255) / 256;
    const int lo = t * chunk;
    const int hi = min(lo + chunk, N);
    int s = 0;
    for (int i = lo; i < hi; ++i) s += in_cnt[i];
    part[t] = s;
    __syncthreads();
    if (t == 0) {
        int a = 0;
        for (int i = 0; i < 256; ++i) { int v = part[i]; part[i] = a; a += v; }
    }
    __syncthreads();
    int a = part[t];
    for (int i = lo; i < hi; ++i) {
        row_ptr[i] = a; cursor[i] = a; a += in_cnt[i];
    }
    if (hi == N) row_ptr[N] = a;
}

// scatter edges into dst-CSR order
__global__ __launch_bounds__(256) void csr_scatter_kernel(
    const int* __restrict__ ei, const float* __restrict__ ea, const int* __restrict__ deg,
    int* cursor, int* src_csr, int* bkt_csr, float* ea_csr, int E)
{
    int e = blockIdx.x * 256 + threadIdx.x;
    if (e >= E) return;
    int s = ei[e], d = ei[E + e];
    int dg = deg[s];
    int b = (dg < MAXD ? dg : MAXD) - 1;
    int pos = atomicAdd(&cursor[d], 1);
    src_csr[pos] = s;
    bkt_csr[pos] = b;
    const float4* p = (const float4*)(ea + (size_t)e * ECH);
    float4* o = (float4*)(ea_csr + (size_t)pos * ECH);
    o[0] = p[0]; o[1] = p[1]; o[2] = p[2]; o[3] = p[3];
}

// ---------------- per-timestep: node transform y = Wx[b]^T x ----------------
// bucket-sorted nodes, tile of 64; Wx[b] (64x64, first 64 rows of W) in LDS.

__global__ __launch_bounds__(256) void y_kernel(
    const float* __restrict__ xin, float* __restrict__ y,
    const int* __restrict__ node_list, const int* __restrict__ deg,
    const float* __restrict__ Wt, int N)
{
    __shared__ float Ws[IN][IN];           // 16 KB
    __shared__ float Ms[IN][TILE_N + 4];   // 17.4 KB
    __shared__ int id_s[TILE_N];
    __shared__ int bkt_s[TILE_N];

    const int t = threadIdx.x;
    const int i0 = blockIdx.x * TILE_N;
    const int ntile = min(TILE_N, N - i0);

    {
        const int e = t >> 2;
        const bool valid = e < ntile;
        const int c0 = (t & 3) * 16;
        const float4 z4 = make_float4(0.f, 0.f, 0.f, 0.f);
        int node = valid ? node_list[i0 + e] : 0;
        const float* xp = xin + (size_t)node * IN + c0;
        #pragma unroll
        for (int i = 0; i < 16; i += 4) {
            float4 v = valid ? *(const float4*)(xp + i) : z4;
            Ms[c0 + i + 0][e] = v.x; Ms[c0 + i + 1][e] = v.y;
            Ms[c0 + i + 2][e] = v.z; Ms[c0 + i + 3][e] = v.w;
        }
        if (t < TILE_N) {
            if (t < ntile) {
                int id = node_list[i0 + t];
                id_s[t] = id;
                int dg = deg[id];
                bkt_s[t] = (dg < MAXD ? dg : MAXD) - 1;
            } else { id_s[t] = 0; bkt_s[t] = -1; }
        }
    }
    __syncthreads();

    const int b_first = bkt_s[0];
    const int b_last = bkt_s[ntile - 1];
    const int eg4 = (t >> 4) * 4;
    const int cg4 = (t & 15) * 4;

    for (int b = b_first; b <= b_last; ++b) {
        if (b != b_first) __syncthreads();
        {
            // first 64 rows (x-part) of W[b] (80x64) are the first 4096 floats
            const float4* Wb = (const float4*)(Wt + (size_t)b * KD * IN);
            float4* Wsp = (float4*)Ws;
            #pragma unroll
            for (int q = 0; q < 4; ++q) Wsp[t + q * 256] = Wb[t + q * 256];
        }
        __syncthreads();

        float acc[4][4];
        #pragma unroll
        for (int e2 = 0; e2 < 4; ++e2)
            #pragma unroll
            for (int c = 0; c < 4; ++c) acc[e2][c] = 0.f;

        #pragma unroll 8
        for (int k = 0; k < IN; ++k) {
            const float4 w = *(const float4*)&Ws[k][cg4];
            const float4 m = *(const float4*)&Ms[k][eg4];
            const float me[4] = {m.x, m.y, m.z, m.w};
            #pragma unroll
            for (int e2 = 0; e2 < 4; ++e2) {
                acc[e2][0] += me[e2] * w.x;
                acc[e2][1] += me[e2] * w.y;
                acc[e2][2] += me[e2] * w.z;
                acc[e2][3] += me[e2] * w.w;
            }
        }

        #pragma unroll
        for (int e2 = 0; e2 < 4; ++e2) {
            const int el = eg4 + e2;
            if (el < ntile && bkt_s[el] == b) {
                float4 v = make_float4(acc[e2][0], acc[e2][1], acc[e2][2], acc[e2][3]);
                *(float4*)(y + (size_t)id_s[el] * IN + cg4) = v;
            }
        }
    }
}

// ---------------- per-timestep: aggregation over dst-CSR ----------------
// out[d] = sigmoid(y[d]) + sum_{e in in(d)} sigmoid(y[src] + We[b]^T ea_e)
// wave-uniform d -> s, b, ea are scalar; y[s] gather coalesced; out written once.

__global__ __launch_bounds__(256) void agg_kernel(
    const float* __restrict__ y, float* __restrict__ out,
    const int* __restrict__ row_ptr, const int* __restrict__ src_csr,
    const int* __restrict__ bkt_csr, const float* __restrict__ ea_csr,
    const float* __restrict__ Wt, int N)
{
    __shared__ float WeL[MAXD][ECH][IN];   // 40 KB
    const int t = threadIdx.x;
    // stage We rows (64..79) of each expert
    for (int idx = t; idx < MAXD * ECH * IN; idx += 256) {
        int b = idx >> 10;          // /1024
        int r = idx & 1023;
        int k = r >> 6;
        int c = r & 63;
        WeL[b][k][c] = Wt[(size_t)b * KD * IN + (size_t)(IN + k) * IN + c];
    }
    __syncthreads();

    const int wave = t >> 6;
    const int c = t & 63;

    #pragma unroll
    for (int i = 0; i < DPB / 4; ++i) {
        const int d = blockIdx.x * DPB + i * 4 + wave;
        if (d >= N) continue;
        const int p0 = row_ptr[d];
        const int p1 = row_ptr[d + 1];
        float acc = sigmoidf(y[(size_t)d * IN + c]);   // self loop
        for (int p = p0; p < p1; ++p) {
            const int s = src_csr[p];
            const int b = bkt_csr[p];
            const float yv = y[(size_t)s * IN + c];
            const float* eap = ea_csr + (size_t)p * ECH;
            float z = 0.f;
            #pragma unroll
            for (int k = 0; k < ECH; ++k) z += eap[k] * WeL[b][k][c];
            acc += sigmoidf(yv + z);
        }
        out[(size_t)d * IN + c] = acc;
    }
}

// ---------------- readout + pooling ----------------

__global__ __launch_bounds__(256) void readout_kernel(
    const float* __restrict__ x, const float* __restrict__ Wr,
    const int* __restrict__ batch, float* __restrict__ pooled, int N)
{
    __shared__ float Wr_s[TSTEPS][10][IN];
    __shared__ float pool_s[64 * 10];
    const int t = threadIdx.x;
    for (int idx = t; idx < TSTEPS * IN * 10; idx += 256) {
        int tt = idx / (IN * 10);
        int r = idx % (IN * 10);
        int k = r / 10;
        int j = r % 10;
        Wr_s[tt][j][k] = Wr[idx];
    }
    for (int idx = t; idx < 64 * 10; idx += 256) pool_s[idx] = 0.f;
    __syncthreads();

    const int n = blockIdx.x * 256 + t;
    if (n < N) {
        float xr[IN];
        const float4* xp = (const float4*)(x + (size_t)n * IN);
        #pragma unroll
        for (int i = 0; i < IN / 4; ++i) ((float4*)xr)[i] = xp[i];
        float out10[10];
        #pragma unroll
        for (int j = 0; j < 10; ++j) out10[j] = 0.f;
        for (int tt = 0; tt < TSTEPS; ++tt) {
            float lg[10];
            #pragma unroll
            for (int j = 0; j < 10; ++j) {
                const float4* wp = (const float4*)Wr_s[tt][j];
                float s = 0.f;
                #pragma unroll
                for (int i = 0; i < IN / 4; ++i) {
                    float4 w = wp[i];
                    float4 xv = ((const float4*)xr)[i];
                    s += w.x * xv.x + w.y * xv.y + w.z * xv.z + w.w * xv.w;
                }
                lg[j] = s;
            }
            float mx = lg[0];
            #pragma unroll
            for (int j = 1; j < 10; ++j) mx = fmaxf(mx, lg[j]);
            float sum = 0.f;
            #pragma unroll
            for (int j = 0; j < 10; ++j) { lg[j] = __expf(lg[j] - mx); sum += lg[j]; }
            float inv = 1.f / sum;
            #pragma unroll
            for (int j = 0; j < 10; ++j) out10[j] += lg[j] * inv;
        }
        const int g = batch[n];
        #pragma unroll
        for (int j = 0; j < 10; ++j) atomicAdd(&pool_s[g * 10 + j], out10[j]);
    }
    __syncthreads();
    for (int idx = t; idx < 64 * 10; idx += 256) {
        float v = pool_s[idx];
        if (v != 0.f) atomicAdd(&pooled[idx], v);
    }
}

// ---------------- final MLP ----------------

__global__ __launch_bounds__(256) void mlp_kernel(
    const float* __restrict__ pooled,
    const float* __restrict__ fc1w, const float* __restrict__ fc1b,
    const float* __restrict__ fc2w, const float* __restrict__ fc2b,
    const float* __restrict__ fc3w, const float* __restrict__ fc3b,
    float* __restrict__ out, int G)
{
    __shared__ float p_s[64 * 10];
    __shared__ float h1[64 * 128];
    __shared__ float h2[64 * 64];
    const int t = threadIdx.x;
    for (int idx = t; idx < G * 10; idx += 256) p_s[idx] = pooled[idx];
    __syncthreads();
    for (int idx = t; idx < G * 128; idx += 256) {
        int g = idx >> 7, j = idx & 127;
        float s = fc1b[j];
        #pragma unroll
        for (int k = 0; k < 10; ++k) s += p_s[g * 10 + k] * fc1w[k * 128 + j];
        h1[idx] = (s > 0.f) ? s : 0.01f * s;
    }
    __syncthreads();
    for (int idx = t; idx < G * 64; idx += 256) {
        int g = idx >> 6, j = idx & 63;
        float s = fc2b[j];
        for (int k = 0; k < 128; ++k) s += h1[(g << 7) + k] * fc2w[(k << 6) + j];
        h2[idx] = (s > 0.f) ? s : 0.01f * s;
    }
    __syncthreads();
    if (t < G) {
        float s = fc3b[0];
        for (int k = 0; k < 64; ++k) s += h2[(t << 6) + k] * fc3w[k];
        out[t] = (s > 0.f) ? s : 0.01f * s;
    }
}

// ---------------- launch ----------------

extern "C" void kernel_launch(void* const* d_in, const int* in_sizes, int n_in,
                              void* d_out, int out_size, void* d_ws, size_t ws_size,
                              hipStream_t stream)
{
    const float* x     = (const float*)d_in[0];
    const float* ea    = (const float*)d_in[1];
    const float* Wmsg  = (const float*)d_in[2];
    const float* Wread = (const float*)d_in[3];
    const float* fc1w  = (const float*)d_in[4];
    const float* fc1b  = (const float*)d_in[5];
    const float* fc2w  = (const float*)d_in[6];
    const float* fc2b  = (const float*)d_in[7];
    const float* fc3w  = (const float*)d_in[8];
    const float* fc3b  = (const float*)d_in[9];
    const int* ei      = (const int*)d_in[10];
    const int* batch   = (const int*)d_in[11];

    const int N = in_sizes[0] / IN;
    const int E = in_sizes[10] / 2;

    char* ws = (char*)d_ws;
    size_t off = 0;
    auto take = [&](size_t bytes) {
        char* p = ws + off;
        off = (off + bytes + 255) & ~(size_t)255;
        return p;
    };
    int* deg       = (int*)take((size_t)N * 4);
    int* meta      = (int*)take(128);          // [0..9]=node cnt, [16..25]=node cursor
    int* node_list = (int*)take((size_t)N * 4);
    int* in_cnt    = (int*)take((size_t)N * 4);
    int* row_ptr   = (int*)take((size_t)(N + 1) * 4);
    int* cursorN   = (int*)take((size_t)N * 4);
    int* src_csr   = (int*)take((size_t)E * 4);
    int* bkt_csr   = (int*)take((size_t)E * 4);
    float* ea_csr  = (float*)take((size_t)E * ECH * 4);
    float* ybuf    = (float*)take((size_t)N * IN * 4);
    float* xbA     = (float*)take((size_t)N * IN * 4);
    float* xbB     = (float*)take((size_t)N * IN * 4);
    float* pooled  = (float*)take(64 * 10 * 4);

    int* nb_cnt = meta;
    int* nb_cursor = meta + 16;

    const int nbN = (N + 255) / 256;
    const int nbE = (E + 255) / 256;

    hipMemsetAsync(meta, 0, 128, stream);
    hipMemsetAsync(in_cnt, 0, (size_t)N * 4, stream);
    deg_init_kernel<<<nbN, 256, 0, stream>>>(deg, N);
    deg_add_kernel<<<nbE, 256, 0, stream>>>(ei, deg, E);
    nb_count_kernel<<<nbN, 256, 0, stream>>>(deg, nb_cnt, N);
    nb_scan_kernel<<<1, 64, 0, stream>>>(nb_cnt, nb_cursor);
    nb_scatter_kernel<<<nbN, 256, 0, stream>>>(deg, nb_cursor, node_list, N);
    in_hist_kernel<<<nbE, 256, 0, stream>>>(ei, in_cnt, E);
    rp_scan_kernel<<<1, 256, 0, stream>>>(in_cnt, row_ptr, cursorN, N);
    csr_scatter_kernel<<<nbE, 256, 0, stream>>>(ei, ea, deg, cursorN,
                                                src_csr, bkt_csr, ea_csr, E);

    const int nblkY = (N + TILE_N - 1) / TILE_N;
    const int nblkA = (N + DPB - 1) / DPB;
    const float* xi = x;
    float* bufs[2] = {xbA, xbB};
    for (int tt = 0; tt < TSTEPS; ++tt) {
        const float* Wt = Wmsg + (size_t)tt * MAXD * KD * IN;
        float* xo = bufs[tt & 1];
        y_kernel<<<nblkY, 256, 0, stream>>>(xi, ybuf, node_list, deg, Wt, N);
        agg_kernel<<<nblkA, 256, 0, stream>>>(ybuf, xo, row_ptr, src_csr,
                                              bkt_csr, ea_csr, Wt, N);
        xi = xo;
    }

    hipMemsetAsync(pooled, 0, 64 * 10 * 4, stream);
    readout_kernel<<<nbN, 256, 0, stream>>>(xi, Wread, batch, pooled, N);
    mlp_kernel<<<1, 256, 0, stream>>>(pooled, fc1w, fc1b, fc2w, fc2b, fc3w, fc3b,
                                      (float*)d_out, out_size);
}

// Round 4
// 380.765 us; speedup vs baseline: 8.1835x; 1.1554x over previous
//
#include <hip/hip_runtime.h>

#define MAXD 10
#define TSTEPS 4
#define KD 80      // IN + EC
#define IN 64
#define ECH 16
#define TILE_N 64  // nodes per block in y_kernel

#define AGG_BLOCK 512
#define AGG_EPW 32                       // edges per wave (serial)
#define AGG_EPB (AGG_BLOCK / 64 * AGG_EPW)  // 256 edges per block

__device__ __forceinline__ float sigmoidf(float v) {
    return 1.0f / (1.0f + __expf(-v));
}

// ---------------- preprocessing ----------------
// deg[] counts out-edges EXCLUDING self loop; bucket = min(deg, MAXD-1).

__global__ __launch_bounds__(256) void hist_kernel(const int* __restrict__ ei,
                                                   int* deg, int* in_cnt, int E) {
    int e = blockIdx.x * 256 + threadIdx.x;
    if (e < E) {
        atomicAdd(&deg[ei[e]], 1);
        atomicAdd(&in_cnt[ei[E + e]], 1);
    }
}

// node bucket histogram (LDS-aggregated)
__global__ __launch_bounds__(256) void nb_count_kernel(const int* __restrict__ deg, int* cnt, int N) {
    __shared__ int h[MAXD];
    const int t = threadIdx.x;
    if (t < MAXD) h[t] = 0;
    __syncthreads();
    int n = blockIdx.x * 256 + t;
    if (n < N) {
        int dg = deg[n];
        int b = (dg < MAXD - 1) ? dg : (MAXD - 1);
        atomicAdd(&h[b], 1);
    }
    __syncthreads();
    if (t < MAXD && h[t] > 0) atomicAdd(&cnt[t], h[t]);
}

__global__ void nb_scan_kernel(const int* __restrict__ cnt, int* cursor) {
    if (threadIdx.x == 0) {
        int acc = 0;
        for (int b = 0; b < MAXD; ++b) { cursor[b] = acc; acc += cnt[b]; }
    }
}

__global__ __launch_bounds__(256) void nb_scatter_kernel(const int* __restrict__ deg,
                                                         int* cursor, int* node_list, int N) {
    __shared__ int h[MAXD];
    __shared__ int base[MAXD];
    const int t = threadIdx.x;
    if (t < MAXD) h[t] = 0;
    __syncthreads();
    const int n = blockIdx.x * 256 + t;
    int b = 0, loc = 0;
    const bool valid = n < N;
    if (valid) {
        int dg = deg[n];
        b = (dg < MAXD - 1) ? dg : (MAXD - 1);
        loc = atomicAdd(&h[b], 1);
    }
    __syncthreads();
    if (t < MAXD) base[t] = (h[t] > 0) ? atomicAdd(&cursor[t], h[t]) : 0;
    __syncthreads();
    if (valid) node_list[base[b] + loc] = n;
}

// single-block exclusive scan of in_cnt[0..N) -> cursor[0..N)
__global__ __launch_bounds__(256) void rp_scan_kernel(const int* __restrict__ in_cnt,
                                                      int* cursor, int N) {
    __shared__ int part[256];
    const int t = threadIdx.x;
    const int chunk = (N + 255) / 256;
    const int lo = t * chunk;
    const int hi = min(lo + chunk, N);
    int s = 0;
    for (int i = lo; i < hi; ++i) s += in_cnt[i];
    part[t] = s;
    __syncthreads();
    if (t == 0) {
        int a = 0;
        for (int i = 0; i < 256; ++i) { int v = part[i]; part[i] = a; a += v; }
    }
    __syncthreads();
    int a = part[t];
    for (int i = lo; i < hi; ++i) { cursor[i] = a; a += in_cnt[i]; }
}

// scatter edges into dst-CSR order (also store dst per edge)
__global__ __launch_bounds__(256) void csr_scatter_kernel(
    const int* __restrict__ ei, const float* __restrict__ ea, const int* __restrict__ deg,
    int* cursor, int* src_csr, int* dst_csr, int* bkt_csr, float* ea_csr, int E)
{
    int e = blockIdx.x * 256 + threadIdx.x;
    if (e >= E) return;
    int s = ei[e], d = ei[E + e];
    int dg = deg[s];
    int b = (dg < MAXD - 1) ? dg : (MAXD - 1);
    int pos = atomicAdd(&cursor[d], 1);
    src_csr[pos] = s;
    dst_csr[pos] = d;
    bkt_csr[pos] = b;
    const float4* p = (const float4*)(ea + (size_t)e * ECH);
    float4* o = (float4*)(ea_csr + (size_t)pos * ECH);
    o[0] = p[0]; o[1] = p[1]; o[2] = p[2]; o[3] = p[3];
}

// ---------------- per-timestep: node transform y = Wx[b]^T x ----------------
// Also initializes out[n] = sigmoid(y[n]) (the self-loop message).

__global__ __launch_bounds__(256) void y_kernel(
    const float* __restrict__ xin, float* __restrict__ y, float* __restrict__ out,
    const int* __restrict__ node_list, const int* __restrict__ deg,
    const float* __restrict__ Wt, int N)
{
    __shared__ float Ws[IN][IN];           // 16 KB
    __shared__ float Ms[IN][TILE_N + 4];   // 17.4 KB
    __shared__ int id_s[TILE_N];
    __shared__ int bkt_s[TILE_N];

    const int t = threadIdx.x;
    const int i0 = blockIdx.x * TILE_N;
    const int ntile = min(TILE_N, N - i0);

    {
        const int e = t >> 2;
        const bool valid = e < ntile;
        const int c0 = (t & 3) * 16;
        const float4 z4 = make_float4(0.f, 0.f, 0.f, 0.f);
        int node = valid ? node_list[i0 + e] : 0;
        const float* xp = xin + (size_t)node * IN + c0;
        #pragma unroll
        for (int i = 0; i < 16; i += 4) {
            float4 v = valid ? *(const float4*)(xp + i) : z4;
            Ms[c0 + i + 0][e] = v.x; Ms[c0 + i + 1][e] = v.y;
            Ms[c0 + i + 2][e] = v.z; Ms[c0 + i + 3][e] = v.w;
        }
        if (t < TILE_N) {
            if (t < ntile) {
                int id = node_list[i0 + t];
                id_s[t] = id;
                int dg = deg[id];
                bkt_s[t] = (dg < MAXD - 1) ? dg : (MAXD - 1);
            } else { id_s[t] = 0; bkt_s[t] = -1; }
        }
    }
    __syncthreads();

    const int b_first = bkt_s[0];
    const int b_last = bkt_s[ntile - 1];
    const int eg4 = (t >> 4) * 4;
    const int cg4 = (t & 15) * 4;

    for (int b = b_first; b <= b_last; ++b) {
        if (b != b_first) __syncthreads();
        {
            const float4* Wb = (const float4*)(Wt + (size_t)b * KD * IN);
            float4* Wsp = (float4*)Ws;
            #pragma unroll
            for (int q = 0; q < 4; ++q) Wsp[t + q * 256] = Wb[t + q * 256];
        }
        __syncthreads();

        float acc[4][4];
        #pragma unroll
        for (int e2 = 0; e2 < 4; ++e2)
            #pragma unroll
            for (int c = 0; c < 4; ++c) acc[e2][c] = 0.f;

        #pragma unroll 8
        for (int k = 0; k < IN; ++k) {
            const float4 w = *(const float4*)&Ws[k][cg4];
            const float4 m = *(const float4*)&Ms[k][eg4];
            const float me[4] = {m.x, m.y, m.z, m.w};
            #pragma unroll
            for (int e2 = 0; e2 < 4; ++e2) {
                acc[e2][0] += me[e2] * w.x;
                acc[e2][1] += me[e2] * w.y;
                acc[e2][2] += me[e2] * w.z;
                acc[e2][3] += me[e2] * w.w;
            }
        }

        #pragma unroll
        for (int e2 = 0; e2 < 4; ++e2) {
            const int el = eg4 + e2;
            if (el < ntile && bkt_s[el] == b) {
                const size_t o = (size_t)id_s[el] * IN + cg4;
                float4 v = make_float4(acc[e2][0], acc[e2][1], acc[e2][2], acc[e2][3]);
                *(float4*)(y + o) = v;
                float4 sv = make_float4(sigmoidf(v.x), sigmoidf(v.y),
                                        sigmoidf(v.z), sigmoidf(v.w));
                *(float4*)(out + o) = sv;
            }
        }
    }
}

// ---------------- per-timestep: edge-parallel aggregation ----------------
// CSR is dst-sorted: each wave walks 32 consecutive edges, accumulating runs
// of equal dst in registers; flush = one 64-lane atomicAdd per run boundary.

__global__ __launch_bounds__(AGG_BLOCK) void agg2_kernel(
    const float* __restrict__ y, float* __restrict__ out,
    const int* __restrict__ src_csr, const int* __restrict__ dst_csr,
    const int* __restrict__ bkt_csr, const float* __restrict__ ea_csr,
    const float* __restrict__ Wt, int E)
{
    __shared__ float WeL[MAXD][ECH][IN];   // 40 KB
    const int t = threadIdx.x;
    // stage We rows (64..79) of each expert, vectorized
    {
        const float4* Wsrc = (const float4*)Wt;
        float4* Wd = (float4*)WeL;
        for (int q = t; q < MAXD * ECH * IN / 4; q += AGG_BLOCK) {
            int b = q >> 8;            // /256
            int r = q & 255;
            Wd[q] = Wsrc[b * (KD * IN / 4) + (IN * IN / 4) + r];
        }
    }
    __syncthreads();

    const int wave = t >> 6;
    const int c = t & 63;
    int e = blockIdx.x * AGG_EPB + wave * AGG_EPW;
    const int e_end = min(e + AGG_EPW, E);
    if (e >= e_end) return;

    int cur_d = dst_csr[e];
    float acc = 0.f;
    for (; e < e_end; ++e) {
        const int d = dst_csr[e];
        if (d != cur_d) {
            atomicAdd(&out[(size_t)cur_d * IN + c], acc);
            acc = 0.f;
            cur_d = d;
        }
        const int s = src_csr[e];
        const int b = bkt_csr[e];
        const float yv = y[(size_t)s * IN + c];
        const float4* eap = (const float4*)(ea_csr + (size_t)e * ECH);
        float z = 0.f;
        #pragma unroll
        for (int q = 0; q < 4; ++q) {
            float4 ev = eap[q];
            z += ev.x * WeL[b][q * 4 + 0][c] + ev.y * WeL[b][q * 4 + 1][c]
               + ev.z * WeL[b][q * 4 + 2][c] + ev.w * WeL[b][q * 4 + 3][c];
        }
        acc += sigmoidf(yv + z);
    }
    atomicAdd(&out[(size_t)cur_d * IN + c], acc);
}

// ---------------- readout + pooling ----------------

__global__ __launch_bounds__(256) void readout_kernel(
    const float* __restrict__ x, const float* __restrict__ Wr,
    const int* __restrict__ batch, float* __restrict__ pooled, int N)
{
    __shared__ float Wr_s[TSTEPS][10][IN];
    __shared__ float pool_s[64 * 10];
    const int t = threadIdx.x;
    for (int idx = t; idx < TSTEPS * IN * 10; idx += 256) {
        int tt = idx / (IN * 10);
        int r = idx % (IN * 10);
        int k = r / 10;
        int j = r % 10;
        Wr_s[tt][j][k] = Wr[idx];
    }
    for (int idx = t; idx < 64 * 10; idx += 256) pool_s[idx] = 0.f;
    __syncthreads();

    const int n = blockIdx.x * 256 + t;
    if (n < N) {
        float xr[IN];
        const float4* xp = (const float4*)(x + (size_t)n * IN);
        #pragma unroll
        for (int i = 0; i < IN / 4; ++i) ((float4*)xr)[i] = xp[i];
        float out10[10];
        #pragma unroll
        for (int j = 0; j < 10; ++j) out10[j] = 0.f;
        for (int tt = 0; tt < TSTEPS; ++tt) {
            float lg[10];
            #pragma unroll
            for (int j = 0; j < 10; ++j) {
                const float4* wp = (const float4*)Wr_s[tt][j];
                float s = 0.f;
                #pragma unroll
                for (int i = 0; i < IN / 4; ++i) {
                    float4 w = wp[i];
                    float4 xv = ((const float4*)xr)[i];
                    s += w.x * xv.x + w.y * xv.y + w.z * xv.z + w.w * xv.w;
                }
                lg[j] = s;
            }
            float mx = lg[0];
            #pragma unroll
            for (int j = 1; j < 10; ++j) mx = fmaxf(mx, lg[j]);
            float sum = 0.f;
            #pragma unroll
            for (int j = 0; j < 10; ++j) { lg[j] = __expf(lg[j] - mx); sum += lg[j]; }
            float inv = 1.f / sum;
            #pragma unroll
            for (int j = 0; j < 10; ++j) out10[j] += lg[j] * inv;
        }
        const int g = batch[n];
        #pragma unroll
        for (int j = 0; j < 10; ++j) atomicAdd(&pool_s[g * 10 + j], out10[j]);
    }
    __syncthreads();
    for (int idx = t; idx < 64 * 10; idx += 256) {
        float v = pool_s[idx];
        if (v != 0.f) atomicAdd(&pooled[idx], v);
    }
}

// ---------------- final MLP ----------------

__global__ __launch_bounds__(256) void mlp_kernel(
    const float* __restrict__ pooled,
    const float* __restrict__ fc1w, const float* __restrict__ fc1b,
    const float* __restrict__ fc2w, const float* __restrict__ fc2b,
    const float* __restrict__ fc3w, const float* __restrict__ fc3b,
    float* __restrict__ out, int G)
{
    __shared__ float p_s[64 * 10];
    __shared__ float h1[64 * 128];
    __shared__ float h2[64 * 64];
    const int t = threadIdx.x;
    for (int idx = t; idx < G * 10; idx += 256) p_s[idx] = pooled[idx];
    __syncthreads();
    for (int idx = t; idx < G * 128; idx += 256) {
        int g = idx >> 7, j = idx & 127;
        float s = fc1b[j];
        #pragma unroll
        for (int k = 0; k < 10; ++k) s += p_s[g * 10 + k] * fc1w[k * 128 + j];
        h1[idx] = (s > 0.f) ? s : 0.01f * s;
    }
    __syncthreads();
    for (int idx = t; idx < G * 64; idx += 256) {
        int g = idx >> 6, j = idx & 63;
        float s = fc2b[j];
        for (int k = 0; k < 128; ++k) s += h1[(g << 7) + k] * fc2w[(k << 6) + j];
        h2[idx] = (s > 0.f) ? s : 0.01f * s;
    }
    __syncthreads();
    if (t < G) {
        float s = fc3b[0];
        for (int k = 0; k < 64; ++k) s += h2[(t << 6) + k] * fc3w[k];
        out[t] = (s > 0.f) ? s : 0.01f * s;
    }
}

// ---------------- launch ----------------

extern "C" void kernel_launch(void* const* d_in, const int* in_sizes, int n_in,
                              void* d_out, int out_size, void* d_ws, size_t ws_size,
                              hipStream_t stream)
{
    const float* x     = (const float*)d_in[0];
    const float* ea    = (const float*)d_in[1];
    const float* Wmsg  = (const float*)d_in[2];
    const float* Wread = (const float*)d_in[3];
    const float* fc1w  = (const float*)d_in[4];
    const float* fc1b  = (const float*)d_in[5];
    const float* fc2w  = (const float*)d_in[6];
    const float* fc2b  = (const float*)d_in[7];
    const float* fc3w  = (const float*)d_in[8];
    const float* fc3b  = (const float*)d_in[9];
    const int* ei      = (const int*)d_in[10];
    const int* batch   = (const int*)d_in[11];

    const int N = in_sizes[0] / IN;
    const int E = in_sizes[10] / 2;

    char* ws = (char*)d_ws;
    size_t off = 0;
    auto take = [&](size_t bytes) {
        char* p = ws + off;
        off = (off + bytes + 255) & ~(size_t)255;
        return p;
    };
    int* deg       = (int*)take((size_t)N * 4);
    int* meta      = (int*)take(128);          // [0..9]=node cnt, [16..25]=node cursor
    int* node_list = (int*)take((size_t)N * 4);
    int* in_cnt    = (int*)take((size_t)N * 4);
    int* cursorN   = (int*)take((size_t)N * 4);
    int* src_csr   = (int*)take((size_t)E * 4);
    int* dst_csr   = (int*)take((size_t)E * 4);
    int* bkt_csr   = (int*)take((size_t)E * 4);
    float* ea_csr  = (float*)take((size_t)E * ECH * 4);
    float* ybuf    = (float*)take((size_t)N * IN * 4);
    float* xbA     = (float*)take((size_t)N * IN * 4);
    float* xbB     = (float*)take((size_t)N * IN * 4);
    float* pooled  = (float*)take(64 * 10 * 4);

    int* nb_cnt = meta;
    int* nb_cursor = meta + 16;

    const int nbN = (N + 255) / 256;
    const int nbE = (E + 255) / 256;

    hipMemsetAsync(meta, 0, 128, stream);
    hipMemsetAsync(deg, 0, (size_t)N * 4, stream);
    hipMemsetAsync(in_cnt, 0, (size_t)N * 4, stream);
    hist_kernel<<<nbE, 256, 0, stream>>>(ei, deg, in_cnt, E);
    nb_count_kernel<<<nbN, 256, 0, stream>>>(deg, nb_cnt, N);
    nb_scan_kernel<<<1, 64, 0, stream>>>(nb_cnt, nb_cursor);
    nb_scatter_kernel<<<nbN, 256, 0, stream>>>(deg, nb_cursor, node_list, N);
    rp_scan_kernel<<<1, 256, 0, stream>>>(in_cnt, cursorN, N);
    csr_scatter_kernel<<<nbE, 256, 0, stream>>>(ei, ea, deg, cursorN,
                                                src_csr, dst_csr, bkt_csr, ea_csr, E);

    const int nblkY = (N + TILE_N - 1) / TILE_N;
    const int nblkA = (E + AGG_EPB - 1) / AGG_EPB;
    const float* xi = x;
    float* bufs[2] = {xbA, xbB};
    for (int tt = 0; tt < TSTEPS; ++tt) {
        const float* Wt = Wmsg + (size_t)tt * MAXD * KD * IN;
        float* xo = bufs[tt & 1];
        y_kernel<<<nblkY, 256, 0, stream>>>(xi, ybuf, xo, node_list, deg, Wt, N);
        agg2_kernel<<<nblkA, AGG_BLOCK, 0, stream>>>(ybuf, xo, src_csr, dst_csr,
                                                     bkt_csr, ea_csr, Wt, E);
        xi = xo;
    }

    hipMemsetAsync(pooled, 0, 64 * 10 * 4, stream);
    readout_kernel<<<nbN, 256, 0, stream>>>(xi, Wread, batch, pooled, N);
    mlp_kernel<<<1, 256, 0, stream>>>(pooled, fc1w, fc1b, fc2w, fc2b, fc3w, fc3b,
                                      (float*)d_out, out_size);
}

// Round 5
// 361.669 us; speedup vs baseline: 8.6156x; 1.0528x over previous
//
#include <hip/hip_runtime.h>

#define MAXD 10
#define TSTEPS 4
#define KD 80      // IN + EC
#define IN 64
#define ECH 16
#define TILE_N 64  // nodes per block in y_kernel

#define AGG_BLOCK 512
#define GEPW 8                    // edges per 16-lane group (serial)
#define AGG_EPB (AGG_BLOCK / 16 * GEPW)   // 256 edges per block

__device__ __forceinline__ float sigmoidf(float v) {
    return 1.0f / (1.0f + __expf(-v));
}

// ---------------- preprocessing ----------------
// deg[] counts out-edges EXCLUDING self loop; bucket = min(deg, MAXD-1).

__global__ __launch_bounds__(256) void hist_kernel(const int* __restrict__ ei,
                                                   int* deg, int* in_cnt, int E) {
    int e = blockIdx.x * 256 + threadIdx.x;
    if (e < E) {
        atomicAdd(&deg[ei[e]], 1);
        atomicAdd(&in_cnt[ei[E + e]], 1);
    }
}

// node bucket histogram (LDS-aggregated)
__global__ __launch_bounds__(256) void nb_count_kernel(const int* __restrict__ deg, int* cnt, int N) {
    __shared__ int h[MAXD];
    const int t = threadIdx.x;
    if (t < MAXD) h[t] = 0;
    __syncthreads();
    int n = blockIdx.x * 256 + t;
    if (n < N) {
        int dg = deg[n];
        int b = (dg < MAXD - 1) ? dg : (MAXD - 1);
        atomicAdd(&h[b], 1);
    }
    __syncthreads();
    if (t < MAXD && h[t] > 0) atomicAdd(&cnt[t], h[t]);
}

// fused: exclusive scan of in_cnt -> cursorN, and 10-bucket scan -> nb_cursor
__global__ __launch_bounds__(256) void scan_kernel(const int* __restrict__ in_cnt,
                                                   int* cursor, const int* __restrict__ nb_cnt,
                                                   int* nb_cursor, int N) {
    __shared__ int part[256];
    const int t = threadIdx.x;
    const int chunk = (N + 255) / 256;
    const int lo = t * chunk;
    const int hi = min(lo + chunk, N);
    int s = 0;
    for (int i = lo; i < hi; ++i) s += in_cnt[i];
    part[t] = s;
    __syncthreads();
    if (t == 0) {
        int a = 0;
        for (int i = 0; i < 256; ++i) { int v = part[i]; part[i] = a; a += v; }
        int acc = 0;
        for (int b = 0; b < MAXD; ++b) { nb_cursor[b] = acc; acc += nb_cnt[b]; }
    }
    __syncthreads();
    int a = part[t];
    for (int i = lo; i < hi; ++i) { cursor[i] = a; a += in_cnt[i]; }
}

__global__ __launch_bounds__(256) void nb_scatter_kernel(const int* __restrict__ deg,
                                                         int* cursor, int* node_list, int N) {
    __shared__ int h[MAXD];
    __shared__ int base[MAXD];
    const int t = threadIdx.x;
    if (t < MAXD) h[t] = 0;
    __syncthreads();
    const int n = blockIdx.x * 256 + t;
    int b = 0, loc = 0;
    const bool valid = n < N;
    if (valid) {
        int dg = deg[n];
        b = (dg < MAXD - 1) ? dg : (MAXD - 1);
        loc = atomicAdd(&h[b], 1);
    }
    __syncthreads();
    if (t < MAXD) base[t] = (h[t] > 0) ? atomicAdd(&cursor[t], h[t]) : 0;
    __syncthreads();
    if (valid) node_list[base[b] + loc] = n;
}

// scatter edges into dst-CSR order (also store dst per edge)
__global__ __launch_bounds__(256) void csr_scatter_kernel(
    const int* __restrict__ ei, const float* __restrict__ ea, const int* __restrict__ deg,
    int* cursor, int* src_csr, int* dst_csr, int* bkt_csr, float* ea_csr, int E)
{
    int e = blockIdx.x * 256 + threadIdx.x;
    if (e >= E) return;
    int s = ei[e], d = ei[E + e];
    int dg = deg[s];
    int b = (dg < MAXD - 1) ? dg : (MAXD - 1);
    int pos = atomicAdd(&cursor[d], 1);
    src_csr[pos] = s;
    dst_csr[pos] = d;
    bkt_csr[pos] = b;
    const float4* p = (const float4*)(ea + (size_t)e * ECH);
    float4* o = (float4*)(ea_csr + (size_t)pos * ECH);
    o[0] = p[0]; o[1] = p[1]; o[2] = p[2]; o[3] = p[3];
}

// ---------------- per-timestep: node transform y = Wx[b]^T x ----------------
// Also initializes out[n] = sigmoid(y[n]) (the self-loop message).

__global__ __launch_bounds__(256) void y_kernel(
    const float* __restrict__ xin, float* __restrict__ y, float* __restrict__ out,
    const int* __restrict__ node_list, const int* __restrict__ deg,
    const float* __restrict__ Wt, int N)
{
    __shared__ float Ws[IN][IN];           // 16 KB
    __shared__ float Ms[IN][TILE_N + 4];   // 17.4 KB
    __shared__ int id_s[TILE_N];
    __shared__ int bkt_s[TILE_N];

    const int t = threadIdx.x;
    const int i0 = blockIdx.x * TILE_N;
    const int ntile = min(TILE_N, N - i0);

    {
        const int e = t >> 2;
        const bool valid = e < ntile;
        const int c0 = (t & 3) * 16;
        const float4 z4 = make_float4(0.f, 0.f, 0.f, 0.f);
        int node = valid ? node_list[i0 + e] : 0;
        const float* xp = xin + (size_t)node * IN + c0;
        #pragma unroll
        for (int i = 0; i < 16; i += 4) {
            float4 v = valid ? *(const float4*)(xp + i) : z4;
            Ms[c0 + i + 0][e] = v.x; Ms[c0 + i + 1][e] = v.y;
            Ms[c0 + i + 2][e] = v.z; Ms[c0 + i + 3][e] = v.w;
        }
        if (t < TILE_N) {
            if (t < ntile) {
                int id = node_list[i0 + t];
                id_s[t] = id;
                int dg = deg[id];
                bkt_s[t] = (dg < MAXD - 1) ? dg : (MAXD - 1);
            } else { id_s[t] = 0; bkt_s[t] = -1; }
        }
    }
    __syncthreads();

    const int b_first = bkt_s[0];
    const int b_last = bkt_s[ntile - 1];
    const int eg4 = (t >> 4) * 4;
    const int cg4 = (t & 15) * 4;

    for (int b = b_first; b <= b_last; ++b) {
        if (b != b_first) __syncthreads();
        {
            const float4* Wb = (const float4*)(Wt + (size_t)b * KD * IN);
            float4* Wsp = (float4*)Ws;
            #pragma unroll
            for (int q = 0; q < 4; ++q) Wsp[t + q * 256] = Wb[t + q * 256];
        }
        __syncthreads();

        float acc[4][4];
        #pragma unroll
        for (int e2 = 0; e2 < 4; ++e2)
            #pragma unroll
            for (int c = 0; c < 4; ++c) acc[e2][c] = 0.f;

        #pragma unroll 8
        for (int k = 0; k < IN; ++k) {
            const float4 w = *(const float4*)&Ws[k][cg4];
            const float4 m = *(const float4*)&Ms[k][eg4];
            const float me[4] = {m.x, m.y, m.z, m.w};
            #pragma unroll
            for (int e2 = 0; e2 < 4; ++e2) {
                acc[e2][0] += me[e2] * w.x;
                acc[e2][1] += me[e2] * w.y;
                acc[e2][2] += me[e2] * w.z;
                acc[e2][3] += me[e2] * w.w;
            }
        }

        #pragma unroll
        for (int e2 = 0; e2 < 4; ++e2) {
            const int el = eg4 + e2;
            if (el < ntile && bkt_s[el] == b) {
                const size_t o = (size_t)id_s[el] * IN + cg4;
                float4 v = make_float4(acc[e2][0], acc[e2][1], acc[e2][2], acc[e2][3]);
                *(float4*)(y + o) = v;
                float4 sv = make_float4(sigmoidf(v.x), sigmoidf(v.y),
                                        sigmoidf(v.z), sigmoidf(v.w));
                *(float4*)(out + o) = sv;
            }
        }
    }
}

// ---------------- per-timestep: edge-parallel aggregation ----------------
// Wave = 4 independent 16-lane groups; each group walks GEPW consecutive
// dst-sorted edges (lane = 4 channels, float4). 4 concurrent y-load chains
// per wave; edge meta distributed via shfl; y prefetched one edge ahead.

__global__ __launch_bounds__(AGG_BLOCK) void agg3_kernel(
    const float* __restrict__ y, float* __restrict__ out,
    const int* __restrict__ src_csr, const int* __restrict__ dst_csr,
    const int* __restrict__ bkt_csr, const float* __restrict__ ea_csr,
    const float* __restrict__ Wt, int E)
{
    __shared__ float WeL[MAXD][ECH][IN];   // 40 KB
    const int t = threadIdx.x;
    {
        const float4* Wsrc = (const float4*)Wt;
        float4* Wd = (float4*)WeL;
        #pragma unroll
        for (int i = 0; i < MAXD * ECH * IN / 4 / AGG_BLOCK; ++i) {
            int q = t + i * AGG_BLOCK;
            int b = q >> 8;            // /256 float4 per bucket
            int r = q & 255;
            Wd[q] = Wsrc[b * (KD * IN / 4) + (IN * IN / 4) + r];
        }
    }
    __syncthreads();

    const int lane = t & 63;
    const int grp = lane >> 4;        // 0..3
    const int gl = lane & 15;         // 0..15
    const int c0 = gl * 4;            // 4 channels per lane
    const int base = blockIdx.x * AGG_EPB + (t >> 6) * (4 * GEPW) + grp * GEPW;
    const int cnt = min(GEPW, E - base);
    if (cnt <= 0) return;

    // per-lane meta prefetch for this group's 8 edges
    const int m_idx = base + (gl & (GEPW - 1));
    int s_r = 0, d_r = -1, b_r = 0;
    if (m_idx < E) { s_r = src_csr[m_idx]; d_r = dst_csr[m_idx]; b_r = bkt_csr[m_idx]; }
    const int lane0 = grp * 16;

    int s0 = __shfl(s_r, lane0);
    int cur_d = __shfl(d_r, lane0);
    float4 yv = *(const float4*)(y + (size_t)s0 * IN + c0);
    float4 acc = make_float4(0.f, 0.f, 0.f, 0.f);

    for (int i = 0; i < cnt; ++i) {
        const int b = __shfl(b_r, lane0 + i);
        const int d = __shfl(d_r, lane0 + i);
        // prefetch next edge's y
        float4 yn = make_float4(0.f, 0.f, 0.f, 0.f);
        if (i + 1 < cnt) {
            int sn = __shfl(s_r, lane0 + i + 1);
            yn = *(const float4*)(y + (size_t)sn * IN + c0);
        }
        if (d != cur_d) {
            float* op = out + (size_t)cur_d * IN + c0;
            atomicAdd(op + 0, acc.x); atomicAdd(op + 1, acc.y);
            atomicAdd(op + 2, acc.z); atomicAdd(op + 3, acc.w);
            acc = make_float4(0.f, 0.f, 0.f, 0.f);
            cur_d = d;
        }
        const float4* eap = (const float4*)(ea_csr + (size_t)(base + i) * ECH);
        const float4 e0 = eap[0], e1 = eap[1], e2 = eap[2], e3 = eap[3];
        const float ev[16] = {e0.x, e0.y, e0.z, e0.w, e1.x, e1.y, e1.z, e1.w,
                              e2.x, e2.y, e2.z, e2.w, e3.x, e3.y, e3.z, e3.w};
        float4 z = make_float4(0.f, 0.f, 0.f, 0.f);
        #pragma unroll
        for (int k = 0; k < ECH; ++k) {
            const float4 w = *(const float4*)&WeL[b][k][c0];
            z.x += ev[k] * w.x; z.y += ev[k] * w.y;
            z.z += ev[k] * w.z; z.w += ev[k] * w.w;
        }
        acc.x += sigmoidf(yv.x + z.x);
        acc.y += sigmoidf(yv.y + z.y);
        acc.z += sigmoidf(yv.z + z.z);
        acc.w += sigmoidf(yv.w + z.w);
        yv = yn;
    }
    float* op = out + (size_t)cur_d * IN + c0;
    atomicAdd(op + 0, acc.x); atomicAdd(op + 1, acc.y);
    atomicAdd(op + 2, acc.z); atomicAdd(op + 3, acc.w);
}

// ---------------- readout + pooling ----------------

__global__ __launch_bounds__(256) void readout_kernel(
    const float* __restrict__ x, const float* __restrict__ Wr,
    const int* __restrict__ batch, float* __restrict__ pooled, int N)
{
    __shared__ float Wr_s[TSTEPS][10][IN];
    __shared__ float pool_s[64 * 10];
    const int t = threadIdx.x;
    for (int idx = t; idx < TSTEPS * IN * 10; idx += 256) {
        int tt = idx / (IN * 10);
        int r = idx % (IN * 10);
        int k = r / 10;
        int j = r % 10;
        Wr_s[tt][j][k] = Wr[idx];
    }
    for (int idx = t; idx < 64 * 10; idx += 256) pool_s[idx] = 0.f;
    __syncthreads();

    const int n = blockIdx.x * 256 + t;
    if (n < N) {
        float xr[IN];
        const float4* xp = (const float4*)(x + (size_t)n * IN);
        #pragma unroll
        for (int i = 0; i < IN / 4; ++i) ((float4*)xr)[i] = xp[i];
        float out10[10];
        #pragma unroll
        for (int j = 0; j < 10; ++j) out10[j] = 0.f;
        for (int tt = 0; tt < TSTEPS; ++tt) {
            float lg[10];
            #pragma unroll
            for (int j = 0; j < 10; ++j) {
                const float4* wp = (const float4*)Wr_s[tt][j];
                float s = 0.f;
                #pragma unroll
                for (int i = 0; i < IN / 4; ++i) {
                    float4 w = wp[i];
                    float4 xv = ((const float4*)xr)[i];
                    s += w.x * xv.x + w.y * xv.y + w.z * xv.z + w.w * xv.w;
                }
                lg[j] = s;
            }
            float mx = lg[0];
            #pragma unroll
            for (int j = 1; j < 10; ++j) mx = fmaxf(mx, lg[j]);
            float sum = 0.f;
            #pragma unroll
            for (int j = 0; j < 10; ++j) { lg[j] = __expf(lg[j] - mx); sum += lg[j]; }
            float inv = 1.f / sum;
            #pragma unroll
            for (int j = 0; j < 10; ++j) out10[j] += lg[j] * inv;
        }
        const int g = batch[n];
        #pragma unroll
        for (int j = 0; j < 10; ++j) atomicAdd(&pool_s[g * 10 + j], out10[j]);
    }
    __syncthreads();
    for (int idx = t; idx < 64 * 10; idx += 256) {
        float v = pool_s[idx];
        if (v != 0.f) atomicAdd(&pooled[idx], v);
    }
}

// ---------------- final MLP ----------------

__global__ __launch_bounds__(256) void mlp_kernel(
    const float* __restrict__ pooled,
    const float* __restrict__ fc1w, const float* __restrict__ fc1b,
    const float* __restrict__ fc2w, const float* __restrict__ fc2b,
    const float* __restrict__ fc3w, const float* __restrict__ fc3b,
    float* __restrict__ out, int G)
{
    __shared__ float p_s[64 * 10];
    __shared__ float h1[64 * 128];
    __shared__ float h2[64 * 64];
    const int t = threadIdx.x;
    for (int idx = t; idx < G * 10; idx += 256) p_s[idx] = pooled[idx];
    __syncthreads();
    for (int idx = t; idx < G * 128; idx += 256) {
        int g = idx >> 7, j = idx & 127;
        float s = fc1b[j];
        #pragma unroll
        for (int k = 0; k < 10; ++k) s += p_s[g * 10 + k] * fc1w[k * 128 + j];
        h1[idx] = (s > 0.f) ? s : 0.01f * s;
    }
    __syncthreads();
    for (int idx = t; idx < G * 64; idx += 256) {
        int g = idx >> 6, j = idx & 63;
        float s = fc2b[j];
        for (int k = 0; k < 128; ++k) s += h1[(g << 7) + k] * fc2w[(k << 6) + j];
        h2[idx] = (s > 0.f) ? s : 0.01f * s;
    }
    __syncthreads();
    if (t < G) {
        float s = fc3b[0];
        for (int k = 0; k < 64; ++k) s += h2[(t << 6) + k] * fc3w[k];
        out[t] = (s > 0.f) ? s : 0.01f * s;
    }
}

// ---------------- launch ----------------

extern "C" void kernel_launch(void* const* d_in, const int* in_sizes, int n_in,
                              void* d_out, int out_size, void* d_ws, size_t ws_size,
                              hipStream_t stream)
{
    const float* x     = (const float*)d_in[0];
    const float* ea    = (const float*)d_in[1];
    const float* Wmsg  = (const float*)d_in[2];
    const float* Wread = (const float*)d_in[3];
    const float* fc1w  = (const float*)d_in[4];
    const float* fc1b  = (const float*)d_in[5];
    const float* fc2w  = (const float*)d_in[6];
    const float* fc2b  = (const float*)d_in[7];
    const float* fc3w  = (const float*)d_in[8];
    const float* fc3b  = (const float*)d_in[9];
    const int* ei      = (const int*)d_in[10];
    const int* batch   = (const int*)d_in[11];

    const int N = in_sizes[0] / IN;
    const int E = in_sizes[10] / 2;

    char* ws = (char*)d_ws;
    size_t off = 0;
    auto take = [&](size_t bytes) {
        char* p = ws + off;
        off = (off + bytes + 255) & ~(size_t)255;
        return p;
    };
    // zero-region: [meta | pooled | deg | in_cnt] — single memset per launch
    int* meta      = (int*)take(128);          // [0..9]=node cnt, [16..25]=node cursor
    float* pooled  = (float*)take(64 * 10 * 4);
    int* deg       = (int*)take((size_t)N * 4);
    int* in_cnt    = (int*)take((size_t)N * 4);
    const size_t zero_bytes = (size_t)((char*)in_cnt - (char*)meta) + (size_t)N * 4;
    int* node_list = (int*)take((size_t)N * 4);
    int* cursorN   = (int*)take((size_t)N * 4);
    int* src_csr   = (int*)take((size_t)E * 4);
    int* dst_csr   = (int*)take((size_t)E * 4);
    int* bkt_csr   = (int*)take((size_t)E * 4);
    float* ea_csr  = (float*)take((size_t)E * ECH * 4);
    float* ybuf    = (float*)take((size_t)N * IN * 4);
    float* xbA     = (float*)take((size_t)N * IN * 4);
    float* xbB     = (float*)take((size_t)N * IN * 4);

    int* nb_cnt = meta;
    int* nb_cursor = meta + 16;

    const int nbN = (N + 255) / 256;
    const int nbE = (E + 255) / 256;

    hipMemsetAsync(meta, 0, zero_bytes, stream);
    hist_kernel<<<nbE, 256, 0, stream>>>(ei, deg, in_cnt, E);
    nb_count_kernel<<<nbN, 256, 0, stream>>>(deg, nb_cnt, N);
    scan_kernel<<<1, 256, 0, stream>>>(in_cnt, cursorN, nb_cnt, nb_cursor, N);
    nb_scatter_kernel<<<nbN, 256, 0, stream>>>(deg, nb_cursor, node_list, N);
    csr_scatter_kernel<<<nbE, 256, 0, stream>>>(ei, ea, deg, cursorN,
                                                src_csr, dst_csr, bkt_csr, ea_csr, E);

    const int nblkY = (N + TILE_N - 1) / TILE_N;
    const int nblkA = (E + AGG_EPB - 1) / AGG_EPB;
    const float* xi = x;
    float* bufs[2] = {xbA, xbB};
    for (int tt = 0; tt < TSTEPS; ++tt) {
        const float* Wt = Wmsg + (size_t)tt * MAXD * KD * IN;
        float* xo = bufs[tt & 1];
        y_kernel<<<nblkY, 256, 0, stream>>>(xi, ybuf, xo, node_list, deg, Wt, N);
        agg3_kernel<<<nblkA, AGG_BLOCK, 0, stream>>>(ybuf, xo, src_csr, dst_csr,
                                                     bkt_csr, ea_csr, Wt, E);
        xi = xo;
    }

    readout_kernel<<<nbN, 256, 0, stream>>>(xi, Wread, batch, pooled, N);
    mlp_kernel<<<1, 256, 0, stream>>>(pooled, fc1w, fc1b, fc2w, fc2b, fc3w, fc3b,
                                      (float*)d_out, out_size);
}